// Round 4
// baseline (101.892 us; speedup 1.0000x reference)
//
#include <hip/hip_runtime.h>

#define NBLK  256
#define IN_F  1024
#define HID_F 1024
#define OUT_F 512
#define BATCH 128

__device__ __forceinline__ float sigm(float v) { return 1.0f / (1.0f + __expf(-v)); }

// Software grid barrier. State (cnt, flag) is zeroed by hipMemsetAsync before
// each kernel launch, so each replay starts clean (replay-deterministic).
// Residency of all 256 blocks is guaranteed: 1024-thr block = 16 waves = 4/SIMD,
// VGPR<=512/wave always fits, LDS 48KB <= 160KB -> >=1 block/CU on 256 CUs.
__device__ __forceinline__ void grid_barrier(unsigned* cnt, unsigned* flag) {
    __syncthreads();
    if (threadIdx.x == 0) {
        __threadfence();  // device-scope: make prior writes visible cross-XCD
        unsigned arrived = __hip_atomic_fetch_add(cnt, 1u, __ATOMIC_ACQ_REL,
                                                  __HIP_MEMORY_SCOPE_AGENT);
        if (arrived == NBLK - 1) {
            __hip_atomic_store(flag, 1u, __ATOMIC_RELEASE, __HIP_MEMORY_SCOPE_AGENT);
        } else {
            while (__hip_atomic_load(flag, __ATOMIC_ACQUIRE,
                                     __HIP_MEMORY_SCOPE_AGENT) == 0u)
                __builtin_amdgcn_s_sleep(2);
        }
        __threadfence();
    }
    __syncthreads();
}

__global__ __launch_bounds__(1024, 2) void fused_all(
    const float* __restrict__ x, const float* __restrict__ w1,
    const float* __restrict__ s1, const float* __restrict__ w2,
    float* __restrict__ AC, float* __restrict__ w2s, float* __restrict__ ht,
    unsigned* __restrict__ bar, float* __restrict__ out)
{
    __shared__ __align__(16) char smem[49152];
    const int tid  = threadIdx.x;
    const int bid  = blockIdx.x;
    const int lane = tid & 63;
    const int wv   = tid >> 6;   // wave id 0..15

    // ---- Phase A: AC[i][j] = (A,C), A = 1-w*s, C = w*(2s-1); w2s = sigm(w2) ----
    {
        const int gtid = bid * 1024 + tid;                // 262144 threads
        const float4 wq = *(const float4*)(w1 + gtid * 4);
        const float4 sq = *(const float4*)(s1 + gtid * 4);
        float4 lo, hi;
        {
            float w_ = sigm(wq.x), s_ = sigm(sq.x);
            lo.x = 1.0f - w_ * s_; lo.y = w_ * (2.0f * s_ - 1.0f);
            w_ = sigm(wq.y); s_ = sigm(sq.y);
            lo.z = 1.0f - w_ * s_; lo.w = w_ * (2.0f * s_ - 1.0f);
            w_ = sigm(wq.z); s_ = sigm(sq.z);
            hi.x = 1.0f - w_ * s_; hi.y = w_ * (2.0f * s_ - 1.0f);
            w_ = sigm(wq.w); s_ = sigm(sq.w);
            hi.z = 1.0f - w_ * s_; hi.w = w_ * (2.0f * s_ - 1.0f);
        }
        *(float4*)(AC + (size_t)gtid * 8)     = lo;
        *(float4*)(AC + (size_t)gtid * 8 + 4) = hi;
        const float2 w2q = *(const float2*)(w2 + gtid * 2);
        float2 r; r.x = sigm(w2q.x); r.y = sigm(w2q.y);
        *(float2*)(w2s + gtid * 2) = r;
    }
    grid_barrier(bar + 0, bar + 1);

    // ---- Phase B: layer 1. Block: 64 j (lanes) x 8 b (regs); 16 waves split i ----
    {
        const int j0 = (bid & 15) * 64;
        const int b0 = (bid >> 4) * 8;
        float* xs = (float*)smem;   // [1024][12] (pad to 48B rows: 16B-aligned b128)
        {
            const int i = tid;
            float v[8];
#pragma unroll
            for (int bb = 0; bb < 8; ++bb) v[bb] = x[(b0 + bb) * IN_F + i];  // coalesced per bb
            *(float4*)(xs + i * 12)     = make_float4(v[0], v[1], v[2], v[3]);
            *(float4*)(xs + i * 12 + 4) = make_float4(v[4], v[5], v[6], v[7]);
        }
        __syncthreads();
        float acc[8];
#pragma unroll
        for (int k = 0; k < 8; ++k) acc[k] = 1.0f;
        const float2* acp = (const float2*)AC + (size_t)(wv * 64) * HID_F + j0 + lane;
        const float*  xp  = xs + (wv * 64) * 12;
        for (int ii = 0; ii < 64; ++ii) {
            const float2 ac = acp[(size_t)ii * HID_F];            // coalesced 512B/wave
            const float4 xa = *(const float4*)(xp + ii * 12);     // uniform -> broadcast
            const float4 xb = *(const float4*)(xp + ii * 12 + 4);
            acc[0] *= fmaf(xa.x, ac.y, ac.x);
            acc[1] *= fmaf(xa.y, ac.y, ac.x);
            acc[2] *= fmaf(xa.z, ac.y, ac.x);
            acc[3] *= fmaf(xa.w, ac.y, ac.x);
            acc[4] *= fmaf(xb.x, ac.y, ac.x);
            acc[5] *= fmaf(xb.y, ac.y, ac.x);
            acc[6] *= fmaf(xb.z, ac.y, ac.x);
            acc[7] *= fmaf(xb.w, ac.y, ac.x);
        }
        __syncthreads();                 // xs dead -> reuse as ps
        float* ps = (float*)smem;        // [16][64][8]
        *(float4*)(ps + (wv * 64 + lane) * 8)     = make_float4(acc[0], acc[1], acc[2], acc[3]);
        *(float4*)(ps + (wv * 64 + lane) * 8 + 4) = make_float4(acc[4], acc[5], acc[6], acc[7]);
        __syncthreads();
        if (tid < 512) {
            const int bb = tid & 7, j = tid >> 3;
            float p = 1.0f;
#pragma unroll
            for (int ww = 0; ww < 16; ++ww) p *= ps[(ww * 64 + j) * 8 + bb];
            ht[(size_t)(j0 + j) * BATCH + b0 + bb] = p;
        }
    }
    grid_barrier(bar + 2, bar + 3);

    // ---- Phase C: layer 2. Block: 64 o (lanes) x 4 b (regs); 16 waves split j ----
    {
        const int o0 = (bid & 7) * 64;
        const int b0 = (bid >> 3) * 4;
        float* hs = (float*)smem;          // [1024][4]
        {
            const int j = tid;
            *(float4*)(hs + j * 4) = *(const float4*)(ht + (size_t)j * BATCH + b0);
        }
        __syncthreads();
        float acc[4];
#pragma unroll
        for (int k = 0; k < 4; ++k) acc[k] = 1.0f;
        const float* wp = w2s + (size_t)(wv * 64) * OUT_F + o0 + lane;
        const float* hp = hs + (wv * 64) * 4;
        for (int jj = 0; jj < 64; ++jj) {
            const float w2v = wp[(size_t)jj * OUT_F];             // coalesced 256B/wave
            const float4 hv = *(const float4*)(hp + jj * 4);      // uniform -> broadcast
            acc[0] *= fmaf(-w2v, hv.x, 1.0f);
            acc[1] *= fmaf(-w2v, hv.y, 1.0f);
            acc[2] *= fmaf(-w2v, hv.z, 1.0f);
            acc[3] *= fmaf(-w2v, hv.w, 1.0f);
        }
        __syncthreads();
        float* ps2 = (float*)(smem + 16384);  // [16][64][4], disjoint from hs
        *(float4*)(ps2 + (wv * 64 + lane) * 4) = make_float4(acc[0], acc[1], acc[2], acc[3]);
        __syncthreads();
        if (tid < 256) {
            const int o = tid & 63, bb = tid >> 6;
            float p = 1.0f;
#pragma unroll
            for (int ww = 0; ww < 16; ++ww) p *= ps2[(ww * 64 + o) * 4 + bb];
            out[(size_t)(b0 + bb) * OUT_F + o0 + o] = 1.0f - p;
        }
    }
}

extern "C" void kernel_launch(void* const* d_in, const int* in_sizes, int n_in,
                              void* d_out, int out_size, void* d_ws, size_t ws_size,
                              hipStream_t stream) {
    const float* x  = (const float*)d_in[0];
    const float* w1 = (const float*)d_in[1];
    const float* s1 = (const float*)d_in[2];
    const float* w2 = (const float*)d_in[3];
    float* out = (float*)d_out;

    // ws layout: [0,32) barrier state | 256: AC 8MB | w2s 2MB | ht 512KB
    unsigned* bar = (unsigned*)d_ws;
    float* AC  = (float*)((char*)d_ws + 256);
    float* w2s = AC + (size_t)2 * IN_F * HID_F;
    float* ht  = w2s + (size_t)HID_F * OUT_F;

    hipMemsetAsync(d_ws, 0, 32, stream);  // reset barrier state each replay
    fused_all<<<NBLK, 1024, 0, stream>>>(x, w1, s1, w2, AC, w2s, ht, bar, out);
}

// Round 5
// 80.296 us; speedup vs baseline: 1.2690x; 1.2690x over previous
//
#include <hip/hip_runtime.h>

#define NBLK  256
#define IN_F  1024
#define HID_F 1024
#define OUT_F 512
#define BATCH 128

__device__ __forceinline__ float sigm(float v) { return 1.0f / (1.0f + __expf(-v)); }

// Software grid barrier, cheap version:
//  - one RELEASE fence per block (writes back this XCD's dirty L2 once)
//  - RELAXED poll (L2-bypassing load to L3, no invalidation per iteration)
//  - one ACQUIRE fence after the flag flips (single L2 invalidate)
// State zeroed by hipMemsetAsync each launch. Residency: 256 blocks on 256
// CUs, 1 block/CU always fits (16 waves, 48KB LDS) -> no deadlock.
__device__ __forceinline__ void grid_barrier(unsigned* cnt, unsigned* flag) {
    __syncthreads();
    if (threadIdx.x == 0) {
        __builtin_amdgcn_fence(__ATOMIC_RELEASE, "agent");   // publish once (wbL2)
        unsigned arrived = __hip_atomic_fetch_add(cnt, 1u, __ATOMIC_RELAXED,
                                                  __HIP_MEMORY_SCOPE_AGENT);
        if (arrived == NBLK - 1) {
            __hip_atomic_store(flag, 1u, __ATOMIC_RELAXED, __HIP_MEMORY_SCOPE_AGENT);
        } else {
            while (__hip_atomic_load(flag, __ATOMIC_RELAXED,
                                     __HIP_MEMORY_SCOPE_AGENT) == 0u)
                __builtin_amdgcn_s_sleep(8);
        }
        __builtin_amdgcn_fence(__ATOMIC_ACQUIRE, "agent");   // invalidate once
    }
    __syncthreads();
}

__global__ __launch_bounds__(1024, 2) void fused_all(
    const float* __restrict__ x, const float* __restrict__ w1,
    const float* __restrict__ s1, const float* __restrict__ w2,
    float* __restrict__ AC, float* __restrict__ w2s, float* __restrict__ ht,
    unsigned* __restrict__ bar, float* __restrict__ out)
{
    __shared__ __align__(16) char smem[49152];
    const int tid  = threadIdx.x;
    const int bid  = blockIdx.x;
    const int lane = tid & 63;
    const int wv   = tid >> 6;   // wave id 0..15

    // ---- Phase A: AC[i][j] = (A,C), A = 1-w*s, C = w*(2s-1); w2s = sigm(w2) ----
    {
        const int gtid = bid * 1024 + tid;                // 262144 threads
        const float4 wq = *(const float4*)(w1 + gtid * 4);
        const float4 sq = *(const float4*)(s1 + gtid * 4);
        float4 lo, hi;
        {
            float w_ = sigm(wq.x), s_ = sigm(sq.x);
            lo.x = 1.0f - w_ * s_; lo.y = w_ * (2.0f * s_ - 1.0f);
            w_ = sigm(wq.y); s_ = sigm(sq.y);
            lo.z = 1.0f - w_ * s_; lo.w = w_ * (2.0f * s_ - 1.0f);
            w_ = sigm(wq.z); s_ = sigm(sq.z);
            hi.x = 1.0f - w_ * s_; hi.y = w_ * (2.0f * s_ - 1.0f);
            w_ = sigm(wq.w); s_ = sigm(sq.w);
            hi.z = 1.0f - w_ * s_; hi.w = w_ * (2.0f * s_ - 1.0f);
        }
        *(float4*)(AC + (size_t)gtid * 8)     = lo;
        *(float4*)(AC + (size_t)gtid * 8 + 4) = hi;
        const float2 w2q = *(const float2*)(w2 + gtid * 2);
        float2 r; r.x = sigm(w2q.x); r.y = sigm(w2q.y);
        *(float2*)(w2s + gtid * 2) = r;
    }
    grid_barrier(bar + 0, bar + 1);

    // ---- Phase B: layer 1. Block: 64 j (lanes) x 8 b (regs); 16 waves split i ----
    {
        const int j0 = (bid & 15) * 64;
        const int b0 = (bid >> 4) * 8;
        float* xs = (float*)smem;   // [1024][12] rows (48B): 16B-aligned float4s
        {
            const int i = tid;
            float v[8];
#pragma unroll
            for (int bb = 0; bb < 8; ++bb) v[bb] = x[(b0 + bb) * IN_F + i];
            *(float4*)(xs + i * 12)     = make_float4(v[0], v[1], v[2], v[3]);
            *(float4*)(xs + i * 12 + 4) = make_float4(v[4], v[5], v[6], v[7]);
        }
        __syncthreads();
        float acc[8];
#pragma unroll
        for (int k = 0; k < 8; ++k) acc[k] = 1.0f;
        const float2* acp = (const float2*)AC + (size_t)(wv * 64) * HID_F + j0 + lane;
        const float*  xp  = xs + (wv * 64) * 12;
#pragma unroll 16
        for (int ii = 0; ii < 64; ++ii) {
            const float2 ac = acp[(size_t)ii * HID_F];            // 16 in flight
            const float4 xa = *(const float4*)(xp + ii * 12);     // uniform broadcast
            const float4 xb = *(const float4*)(xp + ii * 12 + 4);
            acc[0] *= fmaf(xa.x, ac.y, ac.x);
            acc[1] *= fmaf(xa.y, ac.y, ac.x);
            acc[2] *= fmaf(xa.z, ac.y, ac.x);
            acc[3] *= fmaf(xa.w, ac.y, ac.x);
            acc[4] *= fmaf(xb.x, ac.y, ac.x);
            acc[5] *= fmaf(xb.y, ac.y, ac.x);
            acc[6] *= fmaf(xb.z, ac.y, ac.x);
            acc[7] *= fmaf(xb.w, ac.y, ac.x);
        }
        __syncthreads();                 // xs dead -> reuse as ps
        float* ps = (float*)smem;        // [16][64][8]
        *(float4*)(ps + (wv * 64 + lane) * 8)     = make_float4(acc[0], acc[1], acc[2], acc[3]);
        *(float4*)(ps + (wv * 64 + lane) * 8 + 4) = make_float4(acc[4], acc[5], acc[6], acc[7]);
        __syncthreads();
        if (tid < 512) {
            const int bb = tid & 7, j = tid >> 3;
            float p = 1.0f;
#pragma unroll
            for (int ww = 0; ww < 16; ++ww) p *= ps[(ww * 64 + j) * 8 + bb];
            ht[(size_t)(j0 + j) * BATCH + b0 + bb] = p;
        }
    }
    grid_barrier(bar + 2, bar + 3);

    // ---- Phase C: layer 2. Block: 64 o (lanes) x 4 b (regs); 16 waves split j ----
    {
        const int o0 = (bid & 7) * 64;
        const int b0 = (bid >> 3) * 4;
        float* hs = (float*)smem;          // [1024][4]
        {
            const int j = tid;
            *(float4*)(hs + j * 4) = *(const float4*)(ht + (size_t)j * BATCH + b0);
        }
        __syncthreads();
        float acc[4];
#pragma unroll
        for (int k = 0; k < 4; ++k) acc[k] = 1.0f;
        const float* wp = w2s + (size_t)(wv * 64) * OUT_F + o0 + lane;
        const float* hp = hs + (wv * 64) * 4;
#pragma unroll 16
        for (int jj = 0; jj < 64; ++jj) {
            const float w2v = wp[(size_t)jj * OUT_F];             // 16 in flight
            const float4 hv = *(const float4*)(hp + jj * 4);      // uniform broadcast
            acc[0] *= fmaf(-w2v, hv.x, 1.0f);
            acc[1] *= fmaf(-w2v, hv.y, 1.0f);
            acc[2] *= fmaf(-w2v, hv.z, 1.0f);
            acc[3] *= fmaf(-w2v, hv.w, 1.0f);
        }
        __syncthreads();
        float* ps2 = (float*)(smem + 16384);  // [16][64][4], disjoint from hs
        *(float4*)(ps2 + (wv * 64 + lane) * 4) = make_float4(acc[0], acc[1], acc[2], acc[3]);
        __syncthreads();
        if (tid < 256) {
            const int o = tid & 63, bb = tid >> 6;
            float p = 1.0f;
#pragma unroll
            for (int ww = 0; ww < 16; ++ww) p *= ps2[(ww * 64 + o) * 4 + bb];
            out[(size_t)(b0 + bb) * OUT_F + o0 + o] = 1.0f - p;
        }
    }
}

extern "C" void kernel_launch(void* const* d_in, const int* in_sizes, int n_in,
                              void* d_out, int out_size, void* d_ws, size_t ws_size,
                              hipStream_t stream) {
    const float* x  = (const float*)d_in[0];
    const float* w1 = (const float*)d_in[1];
    const float* s1 = (const float*)d_in[2];
    const float* w2 = (const float*)d_in[3];
    float* out = (float*)d_out;

    // ws layout: [0,32) barrier state | 256: AC 8MB | w2s 2MB | ht 512KB
    unsigned* bar = (unsigned*)d_ws;
    float* AC  = (float*)((char*)d_ws + 256);
    float* w2s = AC + (size_t)2 * IN_F * HID_F;
    float* ht  = w2s + (size_t)HID_F * OUT_F;

    hipMemsetAsync(d_ws, 0, 32, stream);  // reset barrier state each replay
    fused_all<<<NBLK, 1024, 0, stream>>>(x, w1, s1, w2, AC, w2s, ht, bar, out);
}

// Round 6
// 42.801 us; speedup vs baseline: 2.3806x; 1.8760x over previous
//
#include <hip/hip_runtime.h>

#define IN_F  1024
#define HID_F 1024
#define OUT_F 512
#define BATCH 128

__device__ __forceinline__ float sigm(float v) { return 1.0f / (1.0f + __expf(-v)); }

// kPre: blocks [0,1024): AC[i][j]=(A,C) interleaved, A=1-w*s, C=w*(2s-1)
//       blocks [1024,1536): w2s = sigm(w2)
//       blocks [1536,1664): transpose x[128][1024] -> xt[1024][128]
__global__ __launch_bounds__(256) void kPre(const float* __restrict__ x,
                                            const float* __restrict__ w1,
                                            const float* __restrict__ s1,
                                            const float* __restrict__ w2,
                                            float* __restrict__ xt,
                                            float* __restrict__ AC,
                                            float* __restrict__ w2s) {
    const int bx = blockIdx.x;
    const int tid = threadIdx.x;
    if (bx < 1024) {
        const int e = (bx * 256 + tid) * 4;
        const float4 wv = *(const float4*)(w1 + e);
        const float4 sv = *(const float4*)(s1 + e);
        float4 lo, hi;
        float w_ = sigm(wv.x), s_ = sigm(sv.x);
        lo.x = 1.0f - w_ * s_; lo.y = w_ * (2.0f * s_ - 1.0f);
        w_ = sigm(wv.y); s_ = sigm(sv.y);
        lo.z = 1.0f - w_ * s_; lo.w = w_ * (2.0f * s_ - 1.0f);
        w_ = sigm(wv.z); s_ = sigm(sv.z);
        hi.x = 1.0f - w_ * s_; hi.y = w_ * (2.0f * s_ - 1.0f);
        w_ = sigm(wv.w); s_ = sigm(sv.w);
        hi.z = 1.0f - w_ * s_; hi.w = w_ * (2.0f * s_ - 1.0f);
        *(float4*)(AC + (size_t)2 * e)     = lo;
        *(float4*)(AC + (size_t)2 * e + 4) = hi;
    } else if (bx < 1536) {
        const int e = ((bx - 1024) * 256 + tid) * 4;
        const float4 wv = *(const float4*)(w2 + e);
        float4 r;
        r.x = sigm(wv.x); r.y = sigm(wv.y); r.z = sigm(wv.z); r.w = sigm(wv.w);
        *(float4*)(w2s + e) = r;
    } else {
        __shared__ float tile[32][33];
        const int bt = bx - 1536;
        const int i0 = (bt & 31) * 32;
        const int b0 = (bt >> 5) * 32;
        const int tx = tid & 31;
        const int ty = tid >> 5;   // 0..7
#pragma unroll
        for (int r = 0; r < 32; r += 8)
            tile[ty + r][tx] = x[(b0 + ty + r) * IN_F + i0 + tx];
        __syncthreads();
#pragma unroll
        for (int r = 0; r < 32; r += 8)
            xt[(i0 + ty + r) * BATCH + b0 + tx] = tile[tx][ty + r];
    }
}

// k1: layer 1. grid (16 j-tiles, 4 b-tiles, 8 i-chunks) = 512 blocks x 256 thr.
// Block: j-tile 64 (lanes), b-tile 32 (4 waves x acc[8]), i-chunk 128.
// AC staged in 4 sub-chunks of 32 i via register double-buffer -> LDS:
// loads for sub-chunk sc+1 are issued before computing sc, so the
// __syncthreads() vmcnt-drain at loop top IS the needed wait (no dead stall).
__global__ __launch_bounds__(256, 2) void k1(const float* __restrict__ AC,
                                             const float* __restrict__ xt,
                                             float* __restrict__ P) {
    __shared__ float xs[128][32];        // [ii][b] 16 KB
    __shared__ float acb[2][32 * 128];   // [buf][ii*128 + jcol] 2x16 KB
    const int tid  = threadIdx.x;
    const int lane = tid & 63, wv = tid >> 6;
    const int j0 = blockIdx.x * 64, b0 = blockIdx.y * 32, i0 = blockIdx.z * 128;

    // x tile stage: thread t covers row ii=t>>1, 16 b at (t&1)*16
    {
        const int ii = tid >> 1, boff = (tid & 1) * 16;
        const float* s = xt + (size_t)(i0 + ii) * BATCH + b0 + boff;
        const float4 a = *(const float4*)s,       b = *(const float4*)(s + 4);
        const float4 c = *(const float4*)(s + 8), d = *(const float4*)(s + 12);
        float* dst = &xs[ii][boff];
        *(float4*)dst = a; *(float4*)(dst + 4) = b;
        *(float4*)(dst + 8) = c; *(float4*)(dst + 12) = d;
    }

    // each thread stages 64B of the 16KB sub-chunk: rows of 128 floats (64j x {A,C})
    const float* gac = AC + (size_t)(i0 + (tid >> 3)) * (HID_F * 2) + j0 * 2 + (tid & 7) * 16;
    float4 R[2][4];
#define LDG_AC(dst, sc) { const float* p_ = gac + (size_t)(sc) * 32 * (HID_F * 2); \
        dst[0] = *(const float4*)p_;        dst[1] = *(const float4*)(p_ + 4); \
        dst[2] = *(const float4*)(p_ + 8);  dst[3] = *(const float4*)(p_ + 12); }
    LDG_AC(R[0], 0);

    float acc[8];
#pragma unroll
    for (int k = 0; k < 8; ++k) acc[k] = 1.0f;

#pragma unroll
    for (int sc = 0; sc < 4; ++sc) {
        __syncthreads();   // drains vmcnt: R[sc&1] complete; prev compute done
        {
            float* d = &acb[sc & 1][tid * 16];
            *(float4*)d        = R[sc & 1][0]; *(float4*)(d + 4)  = R[sc & 1][1];
            *(float4*)(d + 8)  = R[sc & 1][2]; *(float4*)(d + 12) = R[sc & 1][3];
        }
        __syncthreads();   // staged sub-chunk visible to all waves
        if (sc < 3) LDG_AC(R[(sc + 1) & 1], sc + 1);   // flies during compute
        const float* ab = &acb[sc & 1][0];
        const float* xr = &xs[sc * 32][0];
#pragma unroll 8
        for (int ii = 0; ii < 32; ++ii) {
            const float2 ac = *(const float2*)(ab + ii * 128 + lane * 2);
            const float4 xa = *(const float4*)(xr + ii * 32 + wv * 8);
            const float4 xb = *(const float4*)(xr + ii * 32 + wv * 8 + 4);
            acc[0] *= fmaf(xa.x, ac.y, ac.x);
            acc[1] *= fmaf(xa.y, ac.y, ac.x);
            acc[2] *= fmaf(xa.z, ac.y, ac.x);
            acc[3] *= fmaf(xa.w, ac.y, ac.x);
            acc[4] *= fmaf(xb.x, ac.y, ac.x);
            acc[5] *= fmaf(xb.y, ac.y, ac.x);
            acc[6] *= fmaf(xb.z, ac.y, ac.x);
            acc[7] *= fmaf(xb.w, ac.y, ac.x);
        }
    }
    float* Pp = P + ((size_t)blockIdx.z * BATCH + b0 + wv * 8) * HID_F + j0 + lane;
#pragma unroll
    for (int k = 0; k < 8; ++k) Pp[(size_t)k * HID_F] = acc[k];
}

// k2: layer 2 + chunk combine. grid (8 o-tiles, 32 b-tiles of 4) = 256 blocks x 512 thr.
// Stages h (product of 8 P-chunks) into LDS; 8 waves split j (128 each);
// w2s prefetched 16-deep in 2 register banks; final LDS combine + out write.
__global__ __launch_bounds__(512, 2) void k2(const float* __restrict__ w2s,
                                             const float* __restrict__ P,
                                             float* __restrict__ out) {
    __shared__ float hs[4][HID_F];     // 16 KB
    __shared__ float ps[8][64][4];     // 8 KB
    const int tid  = threadIdx.x;
    const int lane = tid & 63, wv = tid >> 6;
    const int o0 = blockIdx.x * 64, b0 = blockIdx.y * 4;

    // h stage with 8-chunk product: thread t: b = t>>7, 8 j at (t&127)*8
    {
        const int b = tid >> 7, jb = (tid & 127) * 8;
        float4 m0 = make_float4(1, 1, 1, 1), m1 = make_float4(1, 1, 1, 1);
#pragma unroll
        for (int c = 0; c < 8; ++c) {
            const float* p = P + ((size_t)c * BATCH + b0 + b) * HID_F + jb;
            const float4 a = *(const float4*)p, q = *(const float4*)(p + 4);
            m0.x *= a.x; m0.y *= a.y; m0.z *= a.z; m0.w *= a.w;
            m1.x *= q.x; m1.y *= q.y; m1.z *= q.z; m1.w *= q.w;
        }
        *(float4*)&hs[b][jb] = m0; *(float4*)&hs[b][jb + 4] = m1;
    }
    __syncthreads();

    float acc[4] = {1.0f, 1.0f, 1.0f, 1.0f};
    const float* wp  = w2s + (size_t)(wv * 128) * OUT_F + o0 + lane;
    const float* hr0 = &hs[0][wv * 128];
    float wb[2][16];
#pragma unroll
    for (int jj = 0; jj < 16; ++jj) wb[0][jj] = wp[(size_t)jj * OUT_F];
#pragma unroll
    for (int blk = 0; blk < 8; ++blk) {
        if (blk < 7) {
#pragma unroll
            for (int jj = 0; jj < 16; ++jj)
                wb[(blk + 1) & 1][jj] = wp[(size_t)((blk + 1) * 16 + jj) * OUT_F];
        }
#pragma unroll
        for (int jj = 0; jj < 16; ++jj) {
            const float w = wb[blk & 1][jj];
            const int j = blk * 16 + jj;                     // rel. to wave base
            acc[0] *= fmaf(-w, hr0[j], 1.0f);                // uniform ds broadcasts
            acc[1] *= fmaf(-w, hr0[HID_F + j], 1.0f);
            acc[2] *= fmaf(-w, hr0[2 * HID_F + j], 1.0f);
            acc[3] *= fmaf(-w, hr0[3 * HID_F + j], 1.0f);
        }
    }
    *(float4*)&ps[wv][lane][0] = make_float4(acc[0], acc[1], acc[2], acc[3]);
    __syncthreads();
    if (tid < 256) {
        const int o = tid & 63, b = tid >> 6;
        float pr = 1.0f;
#pragma unroll
        for (int w = 0; w < 8; ++w) pr *= ps[w][o][b];
        out[(size_t)(b0 + b) * OUT_F + o0 + o] = 1.0f - pr;
    }
}

extern "C" void kernel_launch(void* const* d_in, const int* in_sizes, int n_in,
                              void* d_out, int out_size, void* d_ws, size_t ws_size,
                              hipStream_t stream) {
    const float* x  = (const float*)d_in[0];
    const float* w1 = (const float*)d_in[1];
    const float* s1 = (const float*)d_in[2];
    const float* w2 = (const float*)d_in[3];
    float* out = (float*)d_out;

    // ws layout (floats): AC 8MB | w2s 2MB | xt 512KB | P 4MB
    float* AC  = (float*)d_ws;
    float* w2s = AC + (size_t)2 * IN_F * HID_F;
    float* xt  = w2s + (size_t)HID_F * OUT_F;
    float* P   = xt + (size_t)IN_F * BATCH;

    kPre<<<1664, 256, 0, stream>>>(x, w1, s1, w2, xt, AC, w2s);
    k1<<<dim3(16, 4, 8), 256, 0, stream>>>(AC, xt, P);
    k2<<<dim3(8, 32), 512, 0, stream>>>(w2s, P, out);
}